// Round 10
// baseline (447.144 us; speedup 1.0000x reference)
//
#include <hip/hip_runtime.h>

typedef short bf16x8 __attribute__((ext_vector_type(8)));
typedef float f32x4 __attribute__((ext_vector_type(4)));

#define S_LEN 2048
#define NHEAD 16
#define HSZ 128

__device__ __forceinline__ float bf2f(ushort u) {
    union { unsigned int i; float f; } x; x.i = ((unsigned int)u) << 16; return x.f;
}
__device__ __forceinline__ ushort f2bf(float f) {
    union { float f; unsigned int i; } x; x.f = f;
    unsigned int r = (x.i + 0x7FFFu + ((x.i >> 16) & 1u)) >> 16;
    return (ushort)r;
}

// async global->LDS, 16 B per lane; LDS dest = wave-uniform base + lane*16
__device__ __forceinline__ void gload16(const ushort* g, ushort* l) {
    __builtin_amdgcn_global_load_lds(
        (const __attribute__((address_space(1))) unsigned int*)g,
        (__attribute__((address_space(3))) unsigned int*)l,
        16, 0, 0);
}

#define BAR()   asm volatile("s_barrier" ::: "memory")
#define LGKM0() asm volatile("s_waitcnt lgkmcnt(0)" ::: "memory")

// ---------------- fused prep: cast hidden + transpose both weights ----------------
__device__ __forceinline__ void transpose_body(
    const float* __restrict__ W, ushort* __restrict__ WT,
    int K, int N, int bx, int by, float (*tile)[33]) {
    int tx = threadIdx.x & 31, ty = threadIdx.x >> 5;   // 32 x 8
    int n = bx * 32 + tx;
    #pragma unroll
    for (int j = 0; j < 32; j += 8) {
        int k = by * 32 + ty + j;
        tile[ty + j][tx] = W[(size_t)k * N + n];
    }
    __syncthreads();
    int k2 = by * 32 + tx;
    #pragma unroll
    for (int j = 0; j < 32; j += 8) {
        int n2 = bx * 32 + ty + j;
        WT[(size_t)n2 * K + k2] = f2bf(tile[tx][ty + j]);
    }
}

__global__ __launch_bounds__(256) void prep_kernel(
    const float* __restrict__ hidden, ushort* __restrict__ hA,
    const float* __restrict__ Wqkv, ushort* __restrict__ WqT,
    const float* __restrict__ Wd, ushort* __restrict__ WdT) {
    __shared__ float tile[32][33];
    int bid = blockIdx.x;
    if (bid < 8192) {                       // cast: 2097152 float4s
        int i = bid * 256 + threadIdx.x;
        float4 v = ((const float4*)hidden)[i];
        ushort4 r;
        r.x = f2bf(v.x); r.y = f2bf(v.y); r.z = f2bf(v.z); r.w = f2bf(v.w);
        ((ushort4*)hA)[i] = r;
    } else if (bid < 8192 + 12288) {        // Wqkv: 192 x 64 tiles
        int tb = bid - 8192;
        transpose_body(Wqkv, WqT, 2048, 6144, tb % 192, tb / 192, tile);
    } else {                                // Wd: 64 x 64 tiles
        int tb = bid - 20480;
        transpose_body(Wd, WdT, 2048, 2048, tb % 64, tb / 64, tile);
    }
}

// ---------------- 128x384 bf16 MFMA GEMM (QKV), BK=64, ks-pipelined 2-phase --------
// R10 retile: 256x256 grid was 384 blocks = 1.5 rounds at 1 block/CU (128 KiB LDS)
// -> 2nd round half-empty, Occupancy 15.7%, ~1/3 of wall time idle. 128x384 tile
// gives grid 16x32 = 512 blocks = 2 EXACTLY FULL rounds. N-tile 384 = one head
// section -> h uniform per block; RoPE pairs: wn=0 rotates (nt0,nt1) [Q d=lm,lm+16],
// wn=1 rotates (nt2,nt3) [K d=lm,lm+16]. Same swizzle, same ks-pipeline, 8
// gloads/tile (A:2, B:6), same vmcnt(8) discipline. gridDim.x=16 % 8 == 0 keeps
// 2 B-panels (3 MB) per XCD L2 (R7 lesson: no chunked XCD swizzle on GEMMs).
// LDS: buf[2] x { A: [ks2][128r][4 slot x 8] = 16 KB | B: [g3][ks2][128r][4x8] = 48 KB }.
__global__ __launch_bounds__(512, 2) void gemm_qkv(
    const ushort* __restrict__ A, const ushort* __restrict__ Bt,
    const float* __restrict__ bias, int Kdim,
    ushort* __restrict__ q_out, ushort* __restrict__ k_out, ushort* __restrict__ v_out,
    const int* __restrict__ pos_ids) {
    __shared__ __align__(16) ushort lds[65536];   // 128 KiB
    const int tid = threadIdx.x;
    const int m0 = blockIdx.y * 128, n0 = blockIdx.x * 384;
    const int lane = tid & 63, wid = tid >> 6;
    const int wm = wid >> 2, wn = wid & 3;          // 2 x 4 wave grid
    const int lm = lane & 15, quad = lane >> 4;
    const int cs = (quad ^ ((lm >> 1) & 3)) * 8;    // swizzled frag slot (ushorts)
    // A frag base: row = wm*64 + mt*16 + lm ; offset = row*32 + cs + ks*4096
    const int aOff = (wm * 64 + lm) * 32 + cs;
    // B frag bases per nt: r = wn*96 + nt*16 (+lm); group = r>>7, row-in-group = r&127
    int bOffs[6];
    #pragma unroll
    for (int nt = 0; nt < 6; ++nt) {
        int rb = wn * 96 + nt * 16;
        bOffs[nt] = 8192 + (rb >> 7) * 8192 + ((rb & 127) + lm) * 32 + cs;
    }
    // staging: thread covers row srow (0..127), slot tid&3, pre-swizzled chunk
    const int srow = tid >> 2;
    const int xs8 = ((tid & 3) ^ ((tid >> 3) & 3)) * 8;
    const ushort* pAs = A  + (size_t)(m0 + srow) * Kdim + xs8;
    const ushort* pBs = Bt + (size_t)(n0 + srow) * Kdim + xs8;
    const size_t gK = (size_t)128 * Kdim;           // one 128-row group stride
    const int sw = wid * 512;                       // wave-uniform LDS stage base

    f32x4 acc[4][6];
    #pragma unroll
    for (int i = 0; i < 4; ++i)
        #pragma unroll
        for (int j = 0; j < 6; ++j) acc[i][j] = (f32x4){0.f, 0.f, 0.f, 0.f};

    const int T = Kdim >> 6;   // BK=64

    auto stageB = [&](int t) {   // 6 gloads: 3 groups x 2 ks
        ushort* b = lds + (t & 1) * 32768 + 8192 + sw;
        const ushort* g = pBs + (size_t)t * 64;
        #pragma unroll
        for (int gr = 0; gr < 3; ++gr) {
            gload16(g + gr * gK,      b + gr * 8192);
            gload16(g + gr * gK + 32, b + gr * 8192 + 4096);
        }
    };
    auto stageA = [&](int t) {   // 2 gloads
        ushort* b = lds + (t & 1) * 32768 + sw;
        const ushort* g = pAs + (size_t)t * 64;
        gload16(g,      b);
        gload16(g + 32, b + 4096);
    };

    // prologue: tiles 0 and 1 staged (8 loads each); tile-0's 8 must land
    stageB(0); stageA(0); stageB(1); stageA(1);
    asm volatile("s_waitcnt vmcnt(8)" ::: "memory");
    BAR();

    // C set = frags(tile 0, ks0)
    bf16x8 afC[4], bfC[6], afN[4], bfN[6];
    #pragma unroll
    for (int mt = 0; mt < 4; ++mt) afC[mt] = *(const bf16x8*)(lds + aOff + mt * 512);
    #pragma unroll
    for (int nt = 0; nt < 6; ++nt) bfC[nt] = *(const bf16x8*)(lds + bOffs[nt]);

    for (int t = 0; t < T; ++t) {
        const ushort* buf = lds + (t & 1) * 32768;
        const bool pf = (t + 2 < T);

        // ---- ph0: issue ks1 reads, MFMA ks0 ----
        #pragma unroll
        for (int mt = 0; mt < 4; ++mt) afN[mt] = *(const bf16x8*)(buf + aOff + 4096 + mt * 512);
        #pragma unroll
        for (int nt = 0; nt < 6; ++nt) bfN[nt] = *(const bf16x8*)(buf + bOffs[nt] + 4096);
        __builtin_amdgcn_s_setprio(1);
        #pragma unroll
        for (int mt = 0; mt < 4; ++mt)
            #pragma unroll
            for (int nt = 0; nt < 6; ++nt)
                acc[mt][nt] = __builtin_amdgcn_mfma_f32_16x16x32_bf16(
                    afC[mt], bfC[nt], acc[mt][nt], 0, 0, 0);
        __builtin_amdgcn_s_setprio(0);
        LGKM0();   // all tile-t frag reads retired
        BAR();     // buf[t&1] dead block-wide

        // ---- ph1: stage t+2 into dead buf[t&1]; MFMA ks1 ----
        if (pf) { stageB(t + 2); stageA(t + 2); }
        __builtin_amdgcn_s_setprio(1);
        #pragma unroll
        for (int mt = 0; mt < 4; ++mt)
            #pragma unroll
            for (int nt = 0; nt < 6; ++nt)
                acc[mt][nt] = __builtin_amdgcn_mfma_f32_16x16x32_bf16(
                    afN[mt], bfN[nt], acc[mt][nt], 0, 0, 0);
        __builtin_amdgcn_s_setprio(0);
        if (pf) asm volatile("s_waitcnt vmcnt(8)" ::: "memory");
        else    asm volatile("s_waitcnt vmcnt(0)" ::: "memory");
        BAR();     // tile-(t+1) data published

        // ---- bubble: read (t+1, ks0) into C set ----
        if (t + 1 < T) {
            const ushort* b2 = lds + ((t + 1) & 1) * 32768;
            #pragma unroll
            for (int mt = 0; mt < 4; ++mt) afC[mt] = *(const bf16x8*)(b2 + aOff + mt * 512);
            #pragma unroll
            for (int nt = 0; nt < 6; ++nt) bfC[nt] = *(const bf16x8*)(b2 + bOffs[nt]);
        }
    }

    // ---- epilogue: bias + fused RoPE + scatter (tile = one head section) ----
    const int h = n0 / 384;
    const int rot = (wn == 0 || wn == 1) ? 1 : 0;   // wn0: Q pair (nt0,nt1); wn1: K pair (nt2,nt3)
    const int p0 = (wn == 0) ? 0 : 2;
    float invf = 0.f;
    if (rot) invf = exp2f(-(float)lm * 0.8304820237218405f);  // log2(10000)/16
    #pragma unroll
    for (int mt = 0; mt < 4; ++mt) {
        f32x4 w[6];
        #pragma unroll
        for (int nt = 0; nt < 6; ++nt) {
            float bv = bias[n0 + wn * 96 + nt * 16 + lm];
            #pragma unroll
            for (int i = 0; i < 4; ++i) w[nt][i] = acc[mt][nt][i] + bv;
        }
        const int gm0 = m0 + wm * 64 + mt * 16 + quad * 4;
        const int b0 = gm0 >> 11, s0 = gm0 & 2047;
        if (rot) {
            #pragma unroll
            for (int i = 0; i < 4; ++i) {
                float th = (float)pos_ids[b0 * S_LEN + s0 + i] * invf;
                float sf, cf;
                sincosf(th, &sf, &cf);
                float x1 = w[p0][i], x2 = w[p0 + 1][i];
                w[p0][i]     = x1 * cf - x2 * sf;   // d = lm
                w[p0 + 1][i] = x2 * cf + x1 * sf;   // d = lm + 16
            }
        }
        #pragma unroll
        for (int nt = 0; nt < 6; ++nt) {
            int r = wn * 96 + nt * 16 + lm;
            int tt = r >> 7, d = r & 127;
            if (tt == 2) {
                // V transposed: [bh][d][s]; s = gm0..gm0+3 consecutive -> ushort4
                ushort4 u;
                u.x = f2bf(w[nt][0]); u.y = f2bf(w[nt][1]);
                u.z = f2bf(w[nt][2]); u.w = f2bf(w[nt][3]);
                *(ushort4*)(v_out + ((size_t)(b0 * NHEAD + h) * HSZ + d) * S_LEN + s0) = u;
            } else {
                ushort* dst = (tt == 0) ? q_out : k_out;
                #pragma unroll
                for (int i = 0; i < 4; ++i)
                    dst[((size_t)(b0 * NHEAD + h) * S_LEN + s0 + i) * HSZ + d] = f2bf(w[nt][i]);
            }
        }
    }
}

// ---------------- 128x128 bf16 MFMA GEMM, BK=32, double-buffered LDS ----------------
// (dense projection; grid 512 blocks = 2 exact rounds; default block mapping keeps
// 2 fixed B panels per XCD)
__global__ __launch_bounds__(256) void gemm128(
    const ushort* __restrict__ A, const ushort* __restrict__ Bt,
    const float* __restrict__ bias, float* __restrict__ Cout, int Kdim, int Ndim) {
    __shared__ __align__(16) ushort lA[2][128 * 32];   // 16 KB
    __shared__ __align__(16) ushort lB[2][128 * 32];   // 16 KB
    const int tid = threadIdx.x;
    const int m0 = blockIdx.y * 128, n0 = blockIdx.x * 128;
    const int lane = tid & 63, wid = tid >> 6;
    const int wm = wid >> 1, wn = wid & 1, lm = lane & 15, quad = lane >> 4;
    const int srow = tid >> 2;
    const int gc = (tid & 3) ^ ((tid >> 3) & 3);
    const int wb8 = (wid << 6) * 8;
    const int cs = (quad ^ ((lm >> 1) & 3)) * 8;

    const ushort* pA = A  + (size_t)(m0 + srow) * Kdim + gc * 8;
    const ushort* pB = Bt + (size_t)(n0 + srow) * Kdim + gc * 8;
    const size_t rhalf = (size_t)64 * Kdim;

    const int fA = (wm * 64 + lm) * 32;
    const int fB = (wn * 64 + lm) * 32;

    f32x4 acc[16];
    #pragma unroll
    for (int i = 0; i < 16; ++i) acc[i] = (f32x4){0.f, 0.f, 0.f, 0.f};

    const int T = Kdim >> 5;
    gload16(pA,         lA[0] + wb8);
    gload16(pA + rhalf, lA[0] + 2048 + wb8);
    gload16(pB,         lB[0] + wb8);
    gload16(pB + rhalf, lB[0] + 2048 + wb8);
    pA += 32; pB += 32;

    for (int t = 0; t < T; ++t) {
        __syncthreads();
        const ushort* la = lA[t & 1];
        const ushort* lb = lB[t & 1];
        if (t + 1 < T) {
            ushort* da = lA[(t + 1) & 1];
            ushort* db = lB[(t + 1) & 1];
            gload16(pA,         da + wb8);
            gload16(pA + rhalf, da + 2048 + wb8);
            gload16(pB,         db + wb8);
            gload16(pB + rhalf, db + 2048 + wb8);
            pA += 32; pB += 32;
        }
        bf16x8 af[4], bfr[4];
        #pragma unroll
        for (int t4 = 0; t4 < 4; ++t4) {
            af[t4]  = *(const bf16x8*)(la + fA + t4 * 512 + cs);
            bfr[t4] = *(const bf16x8*)(lb + fB + t4 * 512 + cs);
        }
        #pragma unroll
        for (int mt = 0; mt < 4; ++mt)
            #pragma unroll
            for (int nt = 0; nt < 4; ++nt)
                acc[mt * 4 + nt] = __builtin_amdgcn_mfma_f32_16x16x32_bf16(
                    af[mt], bfr[nt], acc[mt * 4 + nt], 0, 0, 0);
    }

    #pragma unroll
    for (int mt = 0; mt < 4; ++mt) {
        #pragma unroll
        for (int nt = 0; nt < 4; ++nt) {
            f32x4 c = acc[mt * 4 + nt];
            int gn = n0 + wn * 64 + nt * 16 + lm;
            float bv = bias[gn];
            #pragma unroll
            for (int i = 0; i < 4; ++i) {
                int gm = m0 + wm * 64 + mt * 16 + quad * 4 + i;
                Cout[(size_t)gm * Ndim + gn] = c[i] + bv;
            }
        }
    }
}

// ---------------- MFMA flash attention, fixed-shift softmax (R9 structure) ----------
// 8 waves / 256 q-rows per block, KVBLK=128 (16 iterations). Q frags global->reg.
// lK 2x32KB + lV 2x32KB + lP 20KB = 148 KB. XCD swizzle kept.
__global__ __launch_bounds__(512, 2) void attn_mfma(
    const ushort* __restrict__ Q, const ushort* __restrict__ K,
    const ushort* __restrict__ Vt, ushort* __restrict__ O) {
    __shared__ __align__(16) ushort lK[2][128 * 128];  // 65536 B (swizzled)
    __shared__ __align__(16) ushort lVt[2][128 * 128]; // 65536 B (swizzled)
    __shared__ __align__(16) ushort lP[8 * 32 * 40];   // 20480 B  (total 151552 B)

    const int tid = threadIdx.x;                      // 0..511
    const int wid = tid >> 6, lane = tid & 63;
    const int L = lane & 15, quad = lane >> 4;
    const int bid0 = blockIdx.y * 8 + blockIdx.x;
    const int swz = (bid0 & 7) * 32 + (bid0 >> 3);
    const int bh = swz >> 3;
    const int q0 = (swz & 7) * 256;
    const int wq0 = wid * 32;
    const size_t base = (size_t)bh * S_LEN * HSZ;
    const ushort* Qb = Q + base + (size_t)q0 * HSZ;
    const ushort* Kb = K + base;
    const ushort* Vb = Vt + base;                     // [128][2048]
    ushort* lPw = lP + wid * (32 * 40);

    bf16x8 qf[2][4];
    #pragma unroll
    for (int qs = 0; qs < 2; ++qs)
        #pragma unroll
        for (int dc = 0; dc < 4; ++dc)
            qf[qs][dc] = *(const bf16x8*)(Qb + (size_t)(wq0 + qs * 16 + L) * HSZ
                                          + dc * 32 + quad * 8);

    int kx[4];
    #pragma unroll
    for (int dc = 0; dc < 4; ++dc) kx[dc] = ((dc * 4 + quad) ^ (L & 7)) * 8;

    const int sr = tid >> 4;                           // 0..31
    const int sg = (tid & 15) ^ (sr & 7);              // swizzled global chunk
    const int ub = (tid & 0x1C0) * 8;                  // wave-uniform dest base

    f32x4 acc_o[8][2];
    #pragma unroll
    for (int dt = 0; dt < 8; ++dt)
        #pragma unroll
        for (int qs = 0; qs < 2; ++qs) acc_o[dt][qs] = (f32x4){0.f, 0.f, 0.f, 0.f};
    float lacc[2] = {0.f, 0.f};
    const float scale = 0.08838834764831845f;  // 1/sqrt(128)
    const float SHIFT = 12.0f;

    #pragma unroll
    for (int l = 0; l < 4; ++l) {
        int r = sr + l * 32;
        gload16(Kb + (size_t)r * 128 + sg * 8,  lK[0]  + ub + l * 4096);
        gload16(Vb + (size_t)r * 2048 + sg * 8, lVt[0] + ub + l * 4096);
    }

    for (int kt = 0; kt < S_LEN / 128; ++kt) {
        __syncthreads();
        const int cur = kt & 1;
        const ushort* lKc = lK[cur];
        const ushort* lVc = lVt[cur];
        if (kt + 1 < S_LEN / 128) {
            ushort* dK = lK[cur ^ 1];
            ushort* dV = lVt[cur ^ 1];
            int kb = (kt + 1) * 128;
            #pragma unroll
            for (int l = 0; l < 4; ++l) {
                int r = sr + l * 32;
                gload16(Kb + (size_t)(kb + r) * 128 + sg * 8,      dK + ub + l * 4096);
                gload16(Vb + (size_t)r * 2048 + kb + sg * 8,       dV + ub + l * 4096);
            }
        }

        f32x4 sa[8][2];
        #pragma unroll
        for (int t = 0; t < 8; ++t)
            #pragma unroll
            for (int qs = 0; qs < 2; ++qs) sa[t][qs] = (f32x4){0.f, 0.f, 0.f, 0.f};
        #pragma unroll
        for (int t = 0; t < 8; ++t)
            #pragma unroll
            for (int dc = 0; dc < 4; ++dc) {
                bf16x8 kf = *(const bf16x8*)(lKc + (t * 16 + L) * 128 + kx[dc]);
                sa[t][0] = __builtin_amdgcn_mfma_f32_16x16x32_bf16(kf, qf[0][dc], sa[t][0], 0, 0, 0);
                sa[t][1] = __builtin_amdgcn_mfma_f32_16x16x32_bf16(kf, qf[1][dc], sa[t][1], 0, 0, 0);
            }

        #pragma unroll
        for (int h = 0; h < 4; ++h) {
            #pragma unroll
            for (int t2 = 0; t2 < 2; ++t2) {
                int t = h * 2 + t2;
                #pragma unroll
                for (int qs = 0; qs < 2; ++qs) {
                    #pragma unroll
                    for (int r = 0; r < 4; ++r) {
                        float pv = __expf(fmaf(sa[t][qs][r], scale, -SHIFT));
                        lacc[qs] += pv;
                        sa[t][qs][r] = pv;
                    }
                    ushort4 u;
                    u.x = f2bf(sa[t][qs][0]);
                    u.y = f2bf(sa[t][qs][1]);
                    u.z = f2bf(sa[t][qs][2]);
                    u.w = f2bf(sa[t][qs][3]);
                    *(ushort4*)(lPw + (qs * 16 + L) * 40 + t2 * 16 + quad * 4) = u;
                }
            }
            LGKM0();
            bf16x8 pf0 = *(const bf16x8*)(lPw + L * 40 + quad * 8);
            bf16x8 pf1 = *(const bf16x8*)(lPw + (16 + L) * 40 + quad * 8);
            const int vx = ((h * 4 + quad) ^ (L & 7)) * 8;
            #pragma unroll
            for (int dt = 0; dt < 8; ++dt) {
                bf16x8 vf = *(const bf16x8*)(lVc + (dt * 16 + L) * 128 + vx);
                acc_o[dt][0] = __builtin_amdgcn_mfma_f32_16x16x32_bf16(vf, pf0, acc_o[dt][0], 0, 0, 0);
                acc_o[dt][1] = __builtin_amdgcn_mfma_f32_16x16x32_bf16(vf, pf1, acc_o[dt][1], 0, 0, 0);
            }
        }
    }

    const int b = bh >> 4, h = bh & 15;
    #pragma unroll
    for (int qs = 0; qs < 2; ++qs) {
        float l = lacc[qs];
        l += __shfl_xor(l, 16);
        l += __shfl_xor(l, 32);
        float inv = 1.f / l;
        size_t row = ((size_t)(b * S_LEN + q0 + wq0 + qs * 16 + L)) * (NHEAD * HSZ) + h * HSZ;
        #pragma unroll
        for (int dt = 0; dt < 8; ++dt) {
            ushort4 u;
            u.x = f2bf(acc_o[dt][qs][0] * inv);
            u.y = f2bf(acc_o[dt][qs][1] * inv);
            u.z = f2bf(acc_o[dt][qs][2] * inv);
            u.w = f2bf(acc_o[dt][qs][3] * inv);
            *(ushort4*)(O + row + dt * 16 + quad * 4) = u;
        }
    }
}

extern "C" void kernel_launch(void* const* d_in, const int* in_sizes, int n_in,
                              void* d_out, int out_size, void* d_ws, size_t ws_size,
                              hipStream_t stream) {
    const float* hidden = (const float*)d_in[0];
    const int*   pos    = (const int*)d_in[1];
    const float* Wqkv   = (const float*)d_in[2];
    const float* bqkv   = (const float*)d_in[3];
    const float* Wd     = (const float*)d_in[4];
    const float* bd     = (const float*)d_in[5];

    char* ws = (char*)d_ws;
    ushort* hA  = (ushort*)ws;                               // 16 MB (reused as O)
    ushort* WqT = (ushort*)(ws + 16777216ull);               // 24 MB
    ushort* WdT = (ushort*)(ws + 41943040ull);               //  8 MB
    ushort* Qb  = (ushort*)(ws + 50331648ull);               // 16 MB
    ushort* Kb  = (ushort*)(ws + 67108864ull);               // 16 MB
    ushort* Vb  = (ushort*)(ws + 83886080ull);               // 16 MB, V^T [bh][d][s]

    prep_kernel<<<dim3(24576), dim3(256), 0, stream>>>(hidden, hA, Wqkv, WqT, Wd, WdT);

    // 128x384 tiles: grid 16x32 = 512 blocks = 2 exactly-full rounds
    gemm_qkv<<<dim3(16, 32), dim3(512), 0, stream>>>(hA, WqT, bqkv, 2048,
                                                     Qb, Kb, Vb, pos);

    ushort* Obuf = hA;  // hidden bf16 no longer needed
    attn_mfma<<<dim3(8, 32), dim3(512), 0, stream>>>(Qb, Kb, Vb, Obuf);

    gemm128<<<dim3(16, 32), dim3(256), 0, stream>>>(Obuf, WdT, bd, (float*)d_out,
                                                    2048, 2048);
}

// Round 11
// 403.869 us; speedup vs baseline: 1.1071x; 1.1071x over previous
//
#include <hip/hip_runtime.h>

typedef short bf16x8 __attribute__((ext_vector_type(8)));
typedef float f32x4 __attribute__((ext_vector_type(4)));

#define S_LEN 2048
#define NHEAD 16
#define HSZ 128

__device__ __forceinline__ float bf2f(ushort u) {
    union { unsigned int i; float f; } x; x.i = ((unsigned int)u) << 16; return x.f;
}
__device__ __forceinline__ ushort f2bf(float f) {
    union { float f; unsigned int i; } x; x.f = f;
    unsigned int r = (x.i + 0x7FFFu + ((x.i >> 16) & 1u)) >> 16;
    return (ushort)r;
}

// async global->LDS, 16 B per lane; LDS dest = wave-uniform base + lane*16
__device__ __forceinline__ void gload16(const ushort* g, ushort* l) {
    __builtin_amdgcn_global_load_lds(
        (const __attribute__((address_space(1))) unsigned int*)g,
        (__attribute__((address_space(3))) unsigned int*)l,
        16, 0, 0);
}

#define BAR()   asm volatile("s_barrier" ::: "memory")
#define LGKM0() asm volatile("s_waitcnt lgkmcnt(0)" ::: "memory")

// ---------------- fused prep: cast hidden + transpose both weights ----------------
__device__ __forceinline__ void transpose_body(
    const float* __restrict__ W, ushort* __restrict__ WT,
    int K, int N, int bx, int by, float (*tile)[33]) {
    int tx = threadIdx.x & 31, ty = threadIdx.x >> 5;   // 32 x 8
    int n = bx * 32 + tx;
    #pragma unroll
    for (int j = 0; j < 32; j += 8) {
        int k = by * 32 + ty + j;
        tile[ty + j][tx] = W[(size_t)k * N + n];
    }
    __syncthreads();
    int k2 = by * 32 + tx;
    #pragma unroll
    for (int j = 0; j < 32; j += 8) {
        int n2 = bx * 32 + ty + j;
        WT[(size_t)n2 * K + k2] = f2bf(tile[tx][ty + j]);
    }
}

__global__ __launch_bounds__(256) void prep_kernel(
    const float* __restrict__ hidden, ushort* __restrict__ hA,
    const float* __restrict__ Wqkv, ushort* __restrict__ WqT,
    const float* __restrict__ Wd, ushort* __restrict__ WdT) {
    __shared__ float tile[32][33];
    int bid = blockIdx.x;
    if (bid < 8192) {                       // cast: 2097152 float4s
        int i = bid * 256 + threadIdx.x;
        float4 v = ((const float4*)hidden)[i];
        ushort4 r;
        r.x = f2bf(v.x); r.y = f2bf(v.y); r.z = f2bf(v.z); r.w = f2bf(v.w);
        ((ushort4*)hA)[i] = r;
    } else if (bid < 8192 + 12288) {        // Wqkv: 192 x 64 tiles
        int tb = bid - 8192;
        transpose_body(Wqkv, WqT, 2048, 6144, tb % 192, tb / 192, tile);
    } else {                                // Wd: 64 x 64 tiles
        int tb = bid - 20480;
        transpose_body(Wd, WdT, 2048, 2048, tb % 64, tb / 64, tile);
    }
}

// ---------------- 256x256 bf16 MFMA GEMM, BK=64, software-pipelined 2-phase --------
// R9 structure (best measured: 147 us). FROZEN after 6 failed retile/schedule arcs:
// R10's 128x384 retile regressed 147->193 (VALUBusy 17.7->32%: less MFMA amortizing
// the same per-tile fixed cost + more B-frag address VALU). No XCD swizzle
// (gridDim.x=24 % 8 == 0: HW round-robin keeps 3 B-panels/XCD L2 — R6/R7 lesson).
template <int EPI>
__global__ __launch_bounds__(512, 2) void gemm256(
    const ushort* __restrict__ A, const ushort* __restrict__ Bt,
    const float* __restrict__ bias, float* __restrict__ Cout, int Kdim, int Ndim,
    ushort* __restrict__ q_out, ushort* __restrict__ k_out, ushort* __restrict__ v_out,
    const int* __restrict__ pos_ids) {
    __shared__ __align__(16) ushort lds[65536];   // 128 KiB
    const int tid = threadIdx.x;
    const int m0 = blockIdx.y * 256, n0 = blockIdx.x * 256;
    const int lane = tid & 63, wid = tid >> 6;
    const int wm = wid >> 2, wn = wid & 3;          // 2 x 4 wave grid
    const int lm = lane & 15, quad = lane >> 4;
    const int cs = (quad ^ ((lm >> 1) & 3)) * 8;    // swizzled frag slot (ushorts)
    const int aOff = wm * 8192 + lm * 32 + cs;
    const int bOff = 16384 + (wn >> 1) * 8192 + (wn & 1) * 2048 + lm * 32 + cs;
    const int srow = tid >> 2;
    const int xs8 = ((tid & 3) ^ ((tid >> 3) & 3)) * 8;
    const ushort* pAs = A  + (size_t)(m0 + srow) * Kdim + xs8;
    const ushort* pBs = Bt + (size_t)(n0 + srow) * Kdim + xs8;
    const size_t hK = (size_t)128 * Kdim;
    const int sw = wid * 512;

    f32x4 acc[8][4];
    #pragma unroll
    for (int i = 0; i < 8; ++i)
        #pragma unroll
        for (int j = 0; j < 4; ++j) acc[i][j] = (f32x4){0.f, 0.f, 0.f, 0.f};

    const int T = Kdim >> 6;   // BK=64

    auto stageB = [&](int t) {
        ushort* b = lds + (t & 1) * 32768 + 16384 + sw;
        const ushort* g = pBs + (size_t)t * 64;
        gload16(g,            b);
        gload16(g + 32,       b + 4096);
        gload16(g + hK,       b + 8192);
        gload16(g + hK + 32,  b + 12288);
    };
    auto stageA = [&](int t) {
        ushort* b = lds + (t & 1) * 32768 + sw;
        const ushort* g = pAs + (size_t)t * 64;
        gload16(g,            b);
        gload16(g + 32,       b + 4096);
        gload16(g + hK,       b + 8192);
        gload16(g + hK + 32,  b + 12288);
    };

    // prologue: tiles 0 and 1 fully staged; tile-0's 8 loads must land
    stageB(0); stageA(0); stageB(1); stageA(1);
    asm volatile("s_waitcnt vmcnt(8)" ::: "memory");
    BAR();

    // C set = frags(tile 0, ks0)
    bf16x8 afC[8], bfC[4], afN[8], bfN[4];
    #pragma unroll
    for (int mt = 0; mt < 8; ++mt) afC[mt] = *(const bf16x8*)(lds + aOff + mt * 512);
    #pragma unroll
    for (int nt = 0; nt < 4; ++nt) bfC[nt] = *(const bf16x8*)(lds + bOff + nt * 512);

    for (int t = 0; t < T; ++t) {
        const ushort* la = lds + (t & 1) * 32768 + aOff;
        const ushort* lb = lds + (t & 1) * 32768 + bOff;
        const bool pf = (t + 2 < T);

        // ---- ph0: issue ks1 reads, MFMA ks0 ----
        #pragma unroll
        for (int mt = 0; mt < 8; ++mt) afN[mt] = *(const bf16x8*)(la + 4096 + mt * 512);
        #pragma unroll
        for (int nt = 0; nt < 4; ++nt) bfN[nt] = *(const bf16x8*)(lb + 4096 + nt * 512);
        __builtin_amdgcn_s_setprio(1);
        #pragma unroll
        for (int mt = 0; mt < 8; ++mt)
            #pragma unroll
            for (int nt = 0; nt < 4; ++nt)
                acc[mt][nt] = __builtin_amdgcn_mfma_f32_16x16x32_bf16(
                    afC[mt], bfC[nt], acc[mt][nt], 0, 0, 0);
        __builtin_amdgcn_s_setprio(0);
        LGKM0();   // all tile-t frag reads retired
        BAR();     // buf[t&1] regions dead block-wide

        // ---- ph1: stage t+2 into dead buf[t&1]; MFMA ks1 ----
        if (pf) { stageB(t + 2); stageA(t + 2); }
        __builtin_amdgcn_s_setprio(1);
        #pragma unroll
        for (int mt = 0; mt < 8; ++mt)
            #pragma unroll
            for (int nt = 0; nt < 4; ++nt)
                acc[mt][nt] = __builtin_amdgcn_mfma_f32_16x16x32_bf16(
                    afN[mt], bfN[nt], acc[mt][nt], 0, 0, 0);
        __builtin_amdgcn_s_setprio(0);
        if (pf) asm volatile("s_waitcnt vmcnt(8)" ::: "memory");
        else    asm volatile("s_waitcnt vmcnt(0)" ::: "memory");
        BAR();     // buf[(t+1)&1] tile-(t+1) data published

        // ---- bubble: read (t+1, ks0) into C set ----
        if (t + 1 < T) {
            const ushort* la2 = lds + ((t + 1) & 1) * 32768 + aOff;
            const ushort* lb2 = lds + ((t + 1) & 1) * 32768 + bOff;
            #pragma unroll
            for (int mt = 0; mt < 8; ++mt) afC[mt] = *(const bf16x8*)(la2 + aOff - aOff + mt * 512 + (la2 - la2) ) ;
            #pragma unroll
            for (int mt = 0; mt < 8; ++mt) afC[mt] = *(const bf16x8*)(la2 + mt * 512);
            #pragma unroll
            for (int nt = 0; nt < 4; ++nt) bfC[nt] = *(const bf16x8*)(lb2 + nt * 512);
        }
    }

    // ---- epilogue ----
    if (EPI == 0) {
        const int woff = (n0 + wn * 64) % 384;
        const int rot = (woff == 0 || woff == 128) ? 1 : 0;
        float invf = 0.f;
        if (rot) invf = exp2f(-(float)lm * 0.8304820237218405f);  // log2(10000)/16
        const int gnb = n0 + wn * 64 + lm;
        #pragma unroll
        for (int mt = 0; mt < 8; ++mt) {
            f32x4 w[4];
            #pragma unroll
            for (int nt = 0; nt < 4; ++nt) {
                float bv = bias[gnb + nt * 16];
                #pragma unroll
                for (int i = 0; i < 4; ++i) w[nt][i] = acc[mt][nt][i] + bv;
            }
            const int gm0 = m0 + wm * 128 + mt * 16 + quad * 4;
            const int b0 = gm0 >> 11, s0 = gm0 & 2047;
            if (rot) {
                #pragma unroll
                for (int i = 0; i < 4; ++i) {
                    float th = (float)pos_ids[b0 * S_LEN + s0 + i] * invf;
                    float sf, cf;
                    sincosf(th, &sf, &cf);
                    float x1 = w[0][i], x2 = w[1][i];
                    w[0][i] = x1 * cf - x2 * sf;   // d = lm
                    w[1][i] = x2 * cf + x1 * sf;   // d = lm + 16
                }
            }
            #pragma unroll
            for (int nt = 0; nt < 4; ++nt) {
                int gn = gnb + nt * 16;
                int h = gn / 384, r = gn - h * 384;
                int tt = r >> 7, d = r & 127;
                if (tt == 2) {
                    // V transposed: [bh][d][s]; s = gm0..gm0+3 consecutive -> ushort4
                    ushort4 u;
                    u.x = f2bf(w[nt][0]); u.y = f2bf(w[nt][1]);
                    u.z = f2bf(w[nt][2]); u.w = f2bf(w[nt][3]);
                    *(ushort4*)(v_out + ((size_t)(b0 * NHEAD + h) * HSZ + d) * S_LEN + s0) = u;
                } else {
                    ushort* dst = (tt == 0) ? q_out : k_out;
                    #pragma unroll
                    for (int i = 0; i < 4; ++i)
                        dst[((size_t)(b0 * NHEAD + h) * S_LEN + s0 + i) * HSZ + d] = f2bf(w[nt][i]);
                }
            }
        }
    } else {
        #pragma unroll
        for (int mt = 0; mt < 8; ++mt) {
            #pragma unroll
            for (int nt = 0; nt < 4; ++nt) {
                f32x4 c = acc[mt][nt];
                int gn = n0 + wn * 64 + nt * 16 + lm;
                float bv = bias[gn];
                #pragma unroll
                for (int i = 0; i < 4; ++i) {
                    int gm = m0 + wm * 128 + mt * 16 + quad * 4 + i;
                    Cout[(size_t)gm * Ndim + gn] = c[i] + bv;
                }
            }
        }
    }
}

// ---------------- 128x128 bf16 MFMA GEMM, BK=32, double-buffered LDS ----------------
// (dense projection; multi-block/CU; default mapping keeps 2 fixed B panels per XCD)
__global__ __launch_bounds__(256) void gemm128(
    const ushort* __restrict__ A, const ushort* __restrict__ Bt,
    const float* __restrict__ bias, float* __restrict__ Cout, int Kdim, int Ndim) {
    __shared__ __align__(16) ushort lA[2][128 * 32];   // 16 KB
    __shared__ __align__(16) ushort lB[2][128 * 32];   // 16 KB
    const int tid = threadIdx.x;
    const int m0 = blockIdx.y * 128, n0 = blockIdx.x * 128;
    const int lane = tid & 63, wid = tid >> 6;
    const int wm = wid >> 1, wn = wid & 1, lm = lane & 15, quad = lane >> 4;
    const int srow = tid >> 2;
    const int gc = (tid & 3) ^ ((tid >> 3) & 3);
    const int wb8 = (wid << 6) * 8;
    const int cs = (quad ^ ((lm >> 1) & 3)) * 8;

    const ushort* pA = A  + (size_t)(m0 + srow) * Kdim + gc * 8;
    const ushort* pB = Bt + (size_t)(n0 + srow) * Kdim + gc * 8;
    const size_t rhalf = (size_t)64 * Kdim;

    const int fA = (wm * 64 + lm) * 32;
    const int fB = (wn * 64 + lm) * 32;

    f32x4 acc[16];
    #pragma unroll
    for (int i = 0; i < 16; ++i) acc[i] = (f32x4){0.f, 0.f, 0.f, 0.f};

    const int T = Kdim >> 5;
    gload16(pA,         lA[0] + wb8);
    gload16(pA + rhalf, lA[0] + 2048 + wb8);
    gload16(pB,         lB[0] + wb8);
    gload16(pB + rhalf, lB[0] + 2048 + wb8);
    pA += 32; pB += 32;

    for (int t = 0; t < T; ++t) {
        __syncthreads();
        const ushort* la = lA[t & 1];
        const ushort* lb = lB[t & 1];
        if (t + 1 < T) {
            ushort* da = lA[(t + 1) & 1];
            ushort* db = lB[(t + 1) & 1];
            gload16(pA,         da + wb8);
            gload16(pA + rhalf, da + 2048 + wb8);
            gload16(pB,         db + wb8);
            gload16(pB + rhalf, db + 2048 + wb8);
            pA += 32; pB += 32;
        }
        bf16x8 af[4], bfr[4];
        #pragma unroll
        for (int t4 = 0; t4 < 4; ++t4) {
            af[t4]  = *(const bf16x8*)(la + fA + t4 * 512 + cs);
            bfr[t4] = *(const bf16x8*)(lb + fB + t4 * 512 + cs);
        }
        #pragma unroll
        for (int mt = 0; mt < 4; ++mt)
            #pragma unroll
            for (int nt = 0; nt < 4; ++nt)
                acc[mt * 4 + nt] = __builtin_amdgcn_mfma_f32_16x16x32_bf16(
                    af[mt], bfr[nt], acc[mt * 4 + nt], 0, 0, 0);
    }

    #pragma unroll
    for (int mt = 0; mt < 4; ++mt) {
        #pragma unroll
        for (int nt = 0; nt < 4; ++nt) {
            f32x4 c = acc[mt * 4 + nt];
            int gn = n0 + wn * 64 + nt * 16 + lm;
            float bv = bias[gn];
            #pragma unroll
            for (int i = 0; i < 4; ++i) {
                int gm = m0 + wm * 64 + mt * 16 + quad * 4 + i;
                Cout[(size_t)gm * Ndim + gn] = c[i] + bv;
            }
        }
    }
}

// ---------------- MFMA flash attention, fixed-shift softmax (R9 structure) ----------
// 8 waves / 256 q-rows per block, KVBLK=128 (16 iterations). Q frags global->reg.
// lK 2x32KB + lV 2x32KB + lP 20KB = 148 KB. XCD swizzle kept.
// R11 experiment (T5, m191): s_setprio(1) around the QK^T and PV MFMA clusters.
__global__ __launch_bounds__(512, 2) void attn_mfma(
    const ushort* __restrict__ Q, const ushort* __restrict__ K,
    const ushort* __restrict__ Vt, ushort* __restrict__ O) {
    __shared__ __align__(16) ushort lK[2][128 * 128];  // 65536 B (swizzled)
    __shared__ __align__(16) ushort lVt[2][128 * 128]; // 65536 B (swizzled)
    __shared__ __align__(16) ushort lP[8 * 32 * 40];   // 20480 B  (total 151552 B)

    const int tid = threadIdx.x;                      // 0..511
    const int wid = tid >> 6, lane = tid & 63;
    const int L = lane & 15, quad = lane >> 4;
    const int bid0 = blockIdx.y * 8 + blockIdx.x;
    const int swz = (bid0 & 7) * 32 + (bid0 >> 3);
    const int bh = swz >> 3;
    const int q0 = (swz & 7) * 256;
    const int wq0 = wid * 32;
    const size_t base = (size_t)bh * S_LEN * HSZ;
    const ushort* Qb = Q + base + (size_t)q0 * HSZ;
    const ushort* Kb = K + base;
    const ushort* Vb = Vt + base;                     // [128][2048]
    ushort* lPw = lP + wid * (32 * 40);

    bf16x8 qf[2][4];
    #pragma unroll
    for (int qs = 0; qs < 2; ++qs)
        #pragma unroll
        for (int dc = 0; dc < 4; ++dc)
            qf[qs][dc] = *(const bf16x8*)(Qb + (size_t)(wq0 + qs * 16 + L) * HSZ
                                          + dc * 32 + quad * 8);

    int kx[4];
    #pragma unroll
    for (int dc = 0; dc < 4; ++dc) kx[dc] = ((dc * 4 + quad) ^ (L & 7)) * 8;

    const int sr = tid >> 4;                           // 0..31
    const int sg = (tid & 15) ^ (sr & 7);              // swizzled global chunk
    const int ub = (tid & 0x1C0) * 8;                  // wave-uniform dest base

    f32x4 acc_o[8][2];
    #pragma unroll
    for (int dt = 0; dt < 8; ++dt)
        #pragma unroll
        for (int qs = 0; qs < 2; ++qs) acc_o[dt][qs] = (f32x4){0.f, 0.f, 0.f, 0.f};
    float lacc[2] = {0.f, 0.f};
    const float scale = 0.08838834764831845f;  // 1/sqrt(128)
    const float SHIFT = 12.0f;

    #pragma unroll
    for (int l = 0; l < 4; ++l) {
        int r = sr + l * 32;
        gload16(Kb + (size_t)r * 128 + sg * 8,  lK[0]  + ub + l * 4096);
        gload16(Vb + (size_t)r * 2048 + sg * 8, lVt[0] + ub + l * 4096);
    }

    for (int kt = 0; kt < S_LEN / 128; ++kt) {
        __syncthreads();
        const int cur = kt & 1;
        const ushort* lKc = lK[cur];
        const ushort* lVc = lVt[cur];
        if (kt + 1 < S_LEN / 128) {
            ushort* dK = lK[cur ^ 1];
            ushort* dV = lVt[cur ^ 1];
            int kb = (kt + 1) * 128;
            #pragma unroll
            for (int l = 0; l < 4; ++l) {
                int r = sr + l * 32;
                gload16(Kb + (size_t)(kb + r) * 128 + sg * 8,      dK + ub + l * 4096);
                gload16(Vb + (size_t)r * 2048 + kb + sg * 8,       dV + ub + l * 4096);
            }
        }

        f32x4 sa[8][2];
        #pragma unroll
        for (int t = 0; t < 8; ++t)
            #pragma unroll
            for (int qs = 0; qs < 2; ++qs) sa[t][qs] = (f32x4){0.f, 0.f, 0.f, 0.f};
        __builtin_amdgcn_s_setprio(1);
        #pragma unroll
        for (int t = 0; t < 8; ++t)
            #pragma unroll
            for (int dc = 0; dc < 4; ++dc) {
                bf16x8 kf = *(const bf16x8*)(lKc + (t * 16 + L) * 128 + kx[dc]);
                sa[t][0] = __builtin_amdgcn_mfma_f32_16x16x32_bf16(kf, qf[0][dc], sa[t][0], 0, 0, 0);
                sa[t][1] = __builtin_amdgcn_mfma_f32_16x16x32_bf16(kf, qf[1][dc], sa[t][1], 0, 0, 0);
            }
        __builtin_amdgcn_s_setprio(0);

        #pragma unroll
        for (int h = 0; h < 4; ++h) {
            #pragma unroll
            for (int t2 = 0; t2 < 2; ++t2) {
                int t = h * 2 + t2;
                #pragma unroll
                for (int qs = 0; qs < 2; ++qs) {
                    #pragma unroll
                    for (int r = 0; r < 4; ++r) {
                        float pv = __expf(fmaf(sa[t][qs][r], scale, -SHIFT));
                        lacc[qs] += pv;
                        sa[t][qs][r] = pv;
                    }
                    ushort4 u;
                    u.x = f2bf(sa[t][qs][0]);
                    u.y = f2bf(sa[t][qs][1]);
                    u.z = f2bf(sa[t][qs][2]);
                    u.w = f2bf(sa[t][qs][3]);
                    *(ushort4*)(lPw + (qs * 16 + L) * 40 + t2 * 16 + quad * 4) = u;
                }
            }
            LGKM0();
            bf16x8 pf0 = *(const bf16x8*)(lPw + L * 40 + quad * 8);
            bf16x8 pf1 = *(const bf16x8*)(lPw + (16 + L) * 40 + quad * 8);
            const int vx = ((h * 4 + quad) ^ (L & 7)) * 8;
            __builtin_amdgcn_s_setprio(1);
            #pragma unroll
            for (int dt = 0; dt < 8; ++dt) {
                bf16x8 vf = *(const bf16x8*)(lVc + (dt * 16 + L) * 128 + vx);
                acc_o[dt][0] = __builtin_amdgcn_mfma_f32_16x16x32_bf16(vf, pf0, acc_o[dt][0], 0, 0, 0);
                acc_o[dt][1] = __builtin_amdgcn_mfma_f32_16x16x32_bf16(vf, pf1, acc_o[dt][1], 0, 0, 0);
            }
            __builtin_amdgcn_s_setprio(0);
        }
    }

    const int b = bh >> 4, h = bh & 15;
    #pragma unroll
    for (int qs = 0; qs < 2; ++qs) {
        float l = lacc[qs];
        l += __shfl_xor(l, 16);
        l += __shfl_xor(l, 32);
        float inv = 1.f / l;
        size_t row = ((size_t)(b * S_LEN + q0 + wq0 + qs * 16 + L)) * (NHEAD * HSZ) + h * HSZ;
        #pragma unroll
        for (int dt = 0; dt < 8; ++dt) {
            ushort4 u;
            u.x = f2bf(acc_o[dt][qs][0] * inv);
            u.y = f2bf(acc_o[dt][qs][1] * inv);
            u.z = f2bf(acc_o[dt][qs][2] * inv);
            u.w = f2bf(acc_o[dt][qs][3] * inv);
            *(ushort4*)(O + row + dt * 16 + quad * 4) = u;
        }
    }
}

extern "C" void kernel_launch(void* const* d_in, const int* in_sizes, int n_in,
                              void* d_out, int out_size, void* d_ws, size_t ws_size,
                              hipStream_t stream) {
    const float* hidden = (const float*)d_in[0];
    const int*   pos    = (const int*)d_in[1];
    const float* Wqkv   = (const float*)d_in[2];
    const float* bqkv   = (const float*)d_in[3];
    const float* Wd     = (const float*)d_in[4];
    const float* bd     = (const float*)d_in[5];

    char* ws = (char*)d_ws;
    ushort* hA  = (ushort*)ws;                               // 16 MB (reused as O)
    ushort* WqT = (ushort*)(ws + 16777216ull);               // 24 MB
    ushort* WdT = (ushort*)(ws + 41943040ull);               //  8 MB
    ushort* Qb  = (ushort*)(ws + 50331648ull);               // 16 MB
    ushort* Kb  = (ushort*)(ws + 67108864ull);               // 16 MB
    ushort* Vb  = (ushort*)(ws + 83886080ull);               // 16 MB, V^T [bh][d][s]

    prep_kernel<<<dim3(24576), dim3(256), 0, stream>>>(hidden, hA, Wqkv, WqT, Wd, WdT);

    gemm256<0><<<dim3(24, 16), dim3(512), 0, stream>>>(hA, WqT, bqkv, nullptr, 2048, 6144,
                                                       Qb, Kb, Vb, pos);

    ushort* Obuf = hA;  // hidden bf16 no longer needed
    attn_mfma<<<dim3(8, 32), dim3(512), 0, stream>>>(Qb, Kb, Vb, Obuf);

    gemm128<<<dim3(16, 32), dim3(256), 0, stream>>>(Obuf, WdT, bd, (float*)d_out,
                                                    2048, 2048);
}

// Round 12
// 403.786 us; speedup vs baseline: 1.1074x; 1.0002x over previous
//
#include <hip/hip_runtime.h>

typedef short bf16x8 __attribute__((ext_vector_type(8)));
typedef float f32x4 __attribute__((ext_vector_type(4)));

#define S_LEN 2048
#define NHEAD 16
#define HSZ 128

__device__ __forceinline__ float bf2f(ushort u) {
    union { unsigned int i; float f; } x; x.i = ((unsigned int)u) << 16; return x.f;
}
__device__ __forceinline__ ushort f2bf(float f) {
    union { float f; unsigned int i; } x; x.f = f;
    unsigned int r = (x.i + 0x7FFFu + ((x.i >> 16) & 1u)) >> 16;
    return (ushort)r;
}

// async global->LDS, 16 B per lane; LDS dest = wave-uniform base + lane*16
__device__ __forceinline__ void gload16(const ushort* g, ushort* l) {
    __builtin_amdgcn_global_load_lds(
        (const __attribute__((address_space(1))) unsigned int*)g,
        (__attribute__((address_space(3))) unsigned int*)l,
        16, 0, 0);
}

#define BAR()   asm volatile("s_barrier" ::: "memory")
#define LGKM0() asm volatile("s_waitcnt lgkmcnt(0)" ::: "memory")

// ---------------- fused prep: cast hidden + transpose both weights ----------------
__device__ __forceinline__ void transpose_body(
    const float* __restrict__ W, ushort* __restrict__ WT,
    int K, int N, int bx, int by, float (*tile)[33]) {
    int tx = threadIdx.x & 31, ty = threadIdx.x >> 5;   // 32 x 8
    int n = bx * 32 + tx;
    #pragma unroll
    for (int j = 0; j < 32; j += 8) {
        int k = by * 32 + ty + j;
        tile[ty + j][tx] = W[(size_t)k * N + n];
    }
    __syncthreads();
    int k2 = by * 32 + tx;
    #pragma unroll
    for (int j = 0; j < 32; j += 8) {
        int n2 = bx * 32 + ty + j;
        WT[(size_t)n2 * K + k2] = f2bf(tile[tx][ty + j]);
    }
}

__global__ __launch_bounds__(256) void prep_kernel(
    const float* __restrict__ hidden, ushort* __restrict__ hA,
    const float* __restrict__ Wqkv, ushort* __restrict__ WqT,
    const float* __restrict__ Wd, ushort* __restrict__ WdT) {
    __shared__ float tile[32][33];
    int bid = blockIdx.x;
    if (bid < 8192) {                       // cast: 2097152 float4s
        int i = bid * 256 + threadIdx.x;
        float4 v = ((const float4*)hidden)[i];
        ushort4 r;
        r.x = f2bf(v.x); r.y = f2bf(v.y); r.z = f2bf(v.z); r.w = f2bf(v.w);
        ((ushort4*)hA)[i] = r;
    } else if (bid < 8192 + 12288) {        // Wqkv: 192 x 64 tiles
        int tb = bid - 8192;
        transpose_body(Wqkv, WqT, 2048, 6144, tb % 192, tb / 192, tile);
    } else {                                // Wd: 64 x 64 tiles
        int tb = bid - 20480;
        transpose_body(Wd, WdT, 2048, 2048, tb % 64, tb / 64, tile);
    }
}

// ---------------- 256x256 bf16 MFMA GEMM, BK=64, software-pipelined 2-phase --------
// R9 structure, FROZEN (6 failed retile/schedule arcs; R10's 128x384 regressed
// 147->193). R12: removed R11's accidental duplicate bubble-read line -> source
// is byte-identical to R9's gemm256; this round doubles as a variance A/B vs R9
// (147 us) and R11 (171 us, junk line + co-compile perturbation + clock variance).
// No XCD swizzle (gridDim.x=24 % 8 == 0: HW round-robin keeps 3 B-panels/XCD L2).
template <int EPI>
__global__ __launch_bounds__(512, 2) void gemm256(
    const ushort* __restrict__ A, const ushort* __restrict__ Bt,
    const float* __restrict__ bias, float* __restrict__ Cout, int Kdim, int Ndim,
    ushort* __restrict__ q_out, ushort* __restrict__ k_out, ushort* __restrict__ v_out,
    const int* __restrict__ pos_ids) {
    __shared__ __align__(16) ushort lds[65536];   // 128 KiB
    const int tid = threadIdx.x;
    const int m0 = blockIdx.y * 256, n0 = blockIdx.x * 256;
    const int lane = tid & 63, wid = tid >> 6;
    const int wm = wid >> 2, wn = wid & 3;          // 2 x 4 wave grid
    const int lm = lane & 15, quad = lane >> 4;
    const int cs = (quad ^ ((lm >> 1) & 3)) * 8;    // swizzled frag slot (ushorts)
    const int aOff = wm * 8192 + lm * 32 + cs;
    const int bOff = 16384 + (wn >> 1) * 8192 + (wn & 1) * 2048 + lm * 32 + cs;
    const int srow = tid >> 2;
    const int xs8 = ((tid & 3) ^ ((tid >> 3) & 3)) * 8;
    const ushort* pAs = A  + (size_t)(m0 + srow) * Kdim + xs8;
    const ushort* pBs = Bt + (size_t)(n0 + srow) * Kdim + xs8;
    const size_t hK = (size_t)128 * Kdim;
    const int sw = wid * 512;

    f32x4 acc[8][4];
    #pragma unroll
    for (int i = 0; i < 8; ++i)
        #pragma unroll
        for (int j = 0; j < 4; ++j) acc[i][j] = (f32x4){0.f, 0.f, 0.f, 0.f};

    const int T = Kdim >> 6;   // BK=64

    auto stageB = [&](int t) {
        ushort* b = lds + (t & 1) * 32768 + 16384 + sw;
        const ushort* g = pBs + (size_t)t * 64;
        gload16(g,            b);
        gload16(g + 32,       b + 4096);
        gload16(g + hK,       b + 8192);
        gload16(g + hK + 32,  b + 12288);
    };
    auto stageA = [&](int t) {
        ushort* b = lds + (t & 1) * 32768 + sw;
        const ushort* g = pAs + (size_t)t * 64;
        gload16(g,            b);
        gload16(g + 32,       b + 4096);
        gload16(g + hK,       b + 8192);
        gload16(g + hK + 32,  b + 12288);
    };

    // prologue: tiles 0 and 1 fully staged; tile-0's 8 loads must land
    stageB(0); stageA(0); stageB(1); stageA(1);
    asm volatile("s_waitcnt vmcnt(8)" ::: "memory");
    BAR();

    // C set = frags(tile 0, ks0)
    bf16x8 afC[8], bfC[4], afN[8], bfN[4];
    #pragma unroll
    for (int mt = 0; mt < 8; ++mt) afC[mt] = *(const bf16x8*)(lds + aOff + mt * 512);
    #pragma unroll
    for (int nt = 0; nt < 4; ++nt) bfC[nt] = *(const bf16x8*)(lds + bOff + nt * 512);

    for (int t = 0; t < T; ++t) {
        const ushort* la = lds + (t & 1) * 32768 + aOff;
        const ushort* lb = lds + (t & 1) * 32768 + bOff;
        const bool pf = (t + 2 < T);

        // ---- ph0: issue ks1 reads, MFMA ks0 ----
        #pragma unroll
        for (int mt = 0; mt < 8; ++mt) afN[mt] = *(const bf16x8*)(la + 4096 + mt * 512);
        #pragma unroll
        for (int nt = 0; nt < 4; ++nt) bfN[nt] = *(const bf16x8*)(lb + 4096 + nt * 512);
        __builtin_amdgcn_s_setprio(1);
        #pragma unroll
        for (int mt = 0; mt < 8; ++mt)
            #pragma unroll
            for (int nt = 0; nt < 4; ++nt)
                acc[mt][nt] = __builtin_amdgcn_mfma_f32_16x16x32_bf16(
                    afC[mt], bfC[nt], acc[mt][nt], 0, 0, 0);
        __builtin_amdgcn_s_setprio(0);
        LGKM0();   // all tile-t frag reads retired
        BAR();     // buf[t&1] regions dead block-wide

        // ---- ph1: stage t+2 into dead buf[t&1]; MFMA ks1 ----
        if (pf) { stageB(t + 2); stageA(t + 2); }
        __builtin_amdgcn_s_setprio(1);
        #pragma unroll
        for (int mt = 0; mt < 8; ++mt)
            #pragma unroll
            for (int nt = 0; nt < 4; ++nt)
                acc[mt][nt] = __builtin_amdgcn_mfma_f32_16x16x32_bf16(
                    afN[mt], bfN[nt], acc[mt][nt], 0, 0, 0);
        __builtin_amdgcn_s_setprio(0);
        if (pf) asm volatile("s_waitcnt vmcnt(8)" ::: "memory");
        else    asm volatile("s_waitcnt vmcnt(0)" ::: "memory");
        BAR();     // buf[(t+1)&1] tile-(t+1) data published

        // ---- bubble: read (t+1, ks0) into C set ----
        if (t + 1 < T) {
            const ushort* la2 = lds + ((t + 1) & 1) * 32768 + aOff;
            const ushort* lb2 = lds + ((t + 1) & 1) * 32768 + bOff;
            #pragma unroll
            for (int mt = 0; mt < 8; ++mt) afC[mt] = *(const bf16x8*)(la2 + mt * 512);
            #pragma unroll
            for (int nt = 0; nt < 4; ++nt) bfC[nt] = *(const bf16x8*)(lb2 + nt * 512);
        }
    }

    // ---- epilogue ----
    if (EPI == 0) {
        const int woff = (n0 + wn * 64) % 384;
        const int rot = (woff == 0 || woff == 128) ? 1 : 0;
        float invf = 0.f;
        if (rot) invf = exp2f(-(float)lm * 0.8304820237218405f);  // log2(10000)/16
        const int gnb = n0 + wn * 64 + lm;
        #pragma unroll
        for (int mt = 0; mt < 8; ++mt) {
            f32x4 w[4];
            #pragma unroll
            for (int nt = 0; nt < 4; ++nt) {
                float bv = bias[gnb + nt * 16];
                #pragma unroll
                for (int i = 0; i < 4; ++i) w[nt][i] = acc[mt][nt][i] + bv;
            }
            const int gm0 = m0 + wm * 128 + mt * 16 + quad * 4;
            const int b0 = gm0 >> 11, s0 = gm0 & 2047;
            if (rot) {
                #pragma unroll
                for (int i = 0; i < 4; ++i) {
                    float th = (float)pos_ids[b0 * S_LEN + s0 + i] * invf;
                    float sf, cf;
                    sincosf(th, &sf, &cf);
                    float x1 = w[0][i], x2 = w[1][i];
                    w[0][i] = x1 * cf - x2 * sf;   // d = lm
                    w[1][i] = x2 * cf + x1 * sf;   // d = lm + 16
                }
            }
            #pragma unroll
            for (int nt = 0; nt < 4; ++nt) {
                int gn = gnb + nt * 16;
                int h = gn / 384, r = gn - h * 384;
                int tt = r >> 7, d = r & 127;
                if (tt == 2) {
                    // V transposed: [bh][d][s]; s = gm0..gm0+3 consecutive -> ushort4
                    ushort4 u;
                    u.x = f2bf(w[nt][0]); u.y = f2bf(w[nt][1]);
                    u.z = f2bf(w[nt][2]); u.w = f2bf(w[nt][3]);
                    *(ushort4*)(v_out + ((size_t)(b0 * NHEAD + h) * HSZ + d) * S_LEN + s0) = u;
                } else {
                    ushort* dst = (tt == 0) ? q_out : k_out;
                    #pragma unroll
                    for (int i = 0; i < 4; ++i)
                        dst[((size_t)(b0 * NHEAD + h) * S_LEN + s0 + i) * HSZ + d] = f2bf(w[nt][i]);
                }
            }
        }
    } else {
        #pragma unroll
        for (int mt = 0; mt < 8; ++mt) {
            #pragma unroll
            for (int nt = 0; nt < 4; ++nt) {
                f32x4 c = acc[mt][nt];
                int gn = n0 + wn * 64 + nt * 16 + lm;
                float bv = bias[gn];
                #pragma unroll
                for (int i = 0; i < 4; ++i) {
                    int gm = m0 + wm * 128 + mt * 16 + quad * 4 + i;
                    Cout[(size_t)gm * Ndim + gn] = c[i] + bv;
                }
            }
        }
    }
}

// ---------------- 128x128 bf16 MFMA GEMM, BK=32, double-buffered LDS ----------------
// (dense projection; multi-block/CU; default mapping keeps 2 fixed B panels per XCD)
__global__ __launch_bounds__(256) void gemm128(
    const ushort* __restrict__ A, const ushort* __restrict__ Bt,
    const float* __restrict__ bias, float* __restrict__ Cout, int Kdim, int Ndim) {
    __shared__ __align__(16) ushort lA[2][128 * 32];   // 16 KB
    __shared__ __align__(16) ushort lB[2][128 * 32];   // 16 KB
    const int tid = threadIdx.x;
    const int m0 = blockIdx.y * 128, n0 = blockIdx.x * 128;
    const int lane = tid & 63, wid = tid >> 6;
    const int wm = wid >> 1, wn = wid & 1, lm = lane & 15, quad = lane >> 4;
    const int srow = tid >> 2;
    const int gc = (tid & 3) ^ ((tid >> 3) & 3);
    const int wb8 = (wid << 6) * 8;
    const int cs = (quad ^ ((lm >> 1) & 3)) * 8;

    const ushort* pA = A  + (size_t)(m0 + srow) * Kdim + gc * 8;
    const ushort* pB = Bt + (size_t)(n0 + srow) * Kdim + gc * 8;
    const size_t rhalf = (size_t)64 * Kdim;

    const int fA = (wm * 64 + lm) * 32;
    const int fB = (wn * 64 + lm) * 32;

    f32x4 acc[16];
    #pragma unroll
    for (int i = 0; i < 16; ++i) acc[i] = (f32x4){0.f, 0.f, 0.f, 0.f};

    const int T = Kdim >> 5;
    gload16(pA,         lA[0] + wb8);
    gload16(pA + rhalf, lA[0] + 2048 + wb8);
    gload16(pB,         lB[0] + wb8);
    gload16(pB + rhalf, lB[0] + 2048 + wb8);
    pA += 32; pB += 32;

    for (int t = 0; t < T; ++t) {
        __syncthreads();
        const ushort* la = lA[t & 1];
        const ushort* lb = lB[t & 1];
        if (t + 1 < T) {
            ushort* da = lA[(t + 1) & 1];
            ushort* db = lB[(t + 1) & 1];
            gload16(pA,         da + wb8);
            gload16(pA + rhalf, da + 2048 + wb8);
            gload16(pB,         db + wb8);
            gload16(pB + rhalf, db + 2048 + wb8);
            pA += 32; pB += 32;
        }
        bf16x8 af[4], bfr[4];
        #pragma unroll
        for (int t4 = 0; t4 < 4; ++t4) {
            af[t4]  = *(const bf16x8*)(la + fA + t4 * 512 + cs);
            bfr[t4] = *(const bf16x8*)(lb + fB + t4 * 512 + cs);
        }
        #pragma unroll
        for (int mt = 0; mt < 4; ++mt)
            #pragma unroll
            for (int nt = 0; nt < 4; ++nt)
                acc[mt * 4 + nt] = __builtin_amdgcn_mfma_f32_16x16x32_bf16(
                    af[mt], bfr[nt], acc[mt * 4 + nt], 0, 0, 0);
    }

    #pragma unroll
    for (int mt = 0; mt < 4; ++mt) {
        #pragma unroll
        for (int nt = 0; nt < 4; ++nt) {
            f32x4 c = acc[mt * 4 + nt];
            int gn = n0 + wn * 64 + nt * 16 + lm;
            float bv = bias[gn];
            #pragma unroll
            for (int i = 0; i < 4; ++i) {
                int gm = m0 + wm * 64 + mt * 16 + quad * 4 + i;
                Cout[(size_t)gm * Ndim + gn] = c[i] + bv;
            }
        }
    }
}

// ---------------- MFMA flash attention, fixed-shift softmax (R9 structure) ----------
// 8 waves / 256 q-rows per block, KVBLK=128 (16 iterations). Q frags global->reg.
// lK 2x32KB + lV 2x32KB + lP 20KB = 148 KB. XCD swizzle kept.
// T5 setprio around QK^T and PV MFMA clusters (kept from R11: aggregate −27 us
// on the non-gemm remainder, consistent with m191's attn win).
__global__ __launch_bounds__(512, 2) void attn_mfma(
    const ushort* __restrict__ Q, const ushort* __restrict__ K,
    const ushort* __restrict__ Vt, ushort* __restrict__ O) {
    __shared__ __align__(16) ushort lK[2][128 * 128];  // 65536 B (swizzled)
    __shared__ __align__(16) ushort lVt[2][128 * 128]; // 65536 B (swizzled)
    __shared__ __align__(16) ushort lP[8 * 32 * 40];   // 20480 B  (total 151552 B)

    const int tid = threadIdx.x;                      // 0..511
    const int wid = tid >> 6, lane = tid & 63;
    const int L = lane & 15, quad = lane >> 4;
    const int bid0 = blockIdx.y * 8 + blockIdx.x;
    const int swz = (bid0 & 7) * 32 + (bid0 >> 3);
    const int bh = swz >> 3;
    const int q0 = (swz & 7) * 256;
    const int wq0 = wid * 32;
    const size_t base = (size_t)bh * S_LEN * HSZ;
    const ushort* Qb = Q + base + (size_t)q0 * HSZ;
    const ushort* Kb = K + base;
    const ushort* Vb = Vt + base;                     // [128][2048]
    ushort* lPw = lP + wid * (32 * 40);

    bf16x8 qf[2][4];
    #pragma unroll
    for (int qs = 0; qs < 2; ++qs)
        #pragma unroll
        for (int dc = 0; dc < 4; ++dc)
            qf[qs][dc] = *(const bf16x8*)(Qb + (size_t)(wq0 + qs * 16 + L) * HSZ
                                          + dc * 32 + quad * 8);

    int kx[4];
    #pragma unroll
    for (int dc = 0; dc < 4; ++dc) kx[dc] = ((dc * 4 + quad) ^ (L & 7)) * 8;

    const int sr = tid >> 4;                           // 0..31
    const int sg = (tid & 15) ^ (sr & 7);              // swizzled global chunk
    const int ub = (tid & 0x1C0) * 8;                  // wave-uniform dest base

    f32x4 acc_o[8][2];
    #pragma unroll
    for (int dt = 0; dt < 8; ++dt)
        #pragma unroll
        for (int qs = 0; qs < 2; ++qs) acc_o[dt][qs] = (f32x4){0.f, 0.f, 0.f, 0.f};
    float lacc[2] = {0.f, 0.f};
    const float scale = 0.08838834764831845f;  // 1/sqrt(128)
    const float SHIFT = 12.0f;

    #pragma unroll
    for (int l = 0; l < 4; ++l) {
        int r = sr + l * 32;
        gload16(Kb + (size_t)r * 128 + sg * 8,  lK[0]  + ub + l * 4096);
        gload16(Vb + (size_t)r * 2048 + sg * 8, lVt[0] + ub + l * 4096);
    }

    for (int kt = 0; kt < S_LEN / 128; ++kt) {
        __syncthreads();
        const int cur = kt & 1;
        const ushort* lKc = lK[cur];
        const ushort* lVc = lVt[cur];
        if (kt + 1 < S_LEN / 128) {
            ushort* dK = lK[cur ^ 1];
            ushort* dV = lVt[cur ^ 1];
            int kb = (kt + 1) * 128;
            #pragma unroll
            for (int l = 0; l < 4; ++l) {
                int r = sr + l * 32;
                gload16(Kb + (size_t)(kb + r) * 128 + sg * 8,      dK + ub + l * 4096);
                gload16(Vb + (size_t)r * 2048 + kb + sg * 8,       dV + ub + l * 4096);
            }
        }

        f32x4 sa[8][2];
        #pragma unroll
        for (int t = 0; t < 8; ++t)
            #pragma unroll
            for (int qs = 0; qs < 2; ++qs) sa[t][qs] = (f32x4){0.f, 0.f, 0.f, 0.f};
        __builtin_amdgcn_s_setprio(1);
        #pragma unroll
        for (int t = 0; t < 8; ++t)
            #pragma unroll
            for (int dc = 0; dc < 4; ++dc) {
                bf16x8 kf = *(const bf16x8*)(lKc + (t * 16 + L) * 128 + kx[dc]);
                sa[t][0] = __builtin_amdgcn_mfma_f32_16x16x32_bf16(kf, qf[0][dc], sa[t][0], 0, 0, 0);
                sa[t][1] = __builtin_amdgcn_mfma_f32_16x16x32_bf16(kf, qf[1][dc], sa[t][1], 0, 0, 0);
            }
        __builtin_amdgcn_s_setprio(0);

        #pragma unroll
        for (int h = 0; h < 4; ++h) {
            #pragma unroll
            for (int t2 = 0; t2 < 2; ++t2) {
                int t = h * 2 + t2;
                #pragma unroll
                for (int qs = 0; qs < 2; ++qs) {
                    #pragma unroll
                    for (int r = 0; r < 4; ++r) {
                        float pv = __expf(fmaf(sa[t][qs][r], scale, -SHIFT));
                        lacc[qs] += pv;
                        sa[t][qs][r] = pv;
                    }
                    ushort4 u;
                    u.x = f2bf(sa[t][qs][0]);
                    u.y = f2bf(sa[t][qs][1]);
                    u.z = f2bf(sa[t][qs][2]);
                    u.w = f2bf(sa[t][qs][3]);
                    *(ushort4*)(lPw + (qs * 16 + L) * 40 + t2 * 16 + quad * 4) = u;
                }
            }
            LGKM0();
            bf16x8 pf0 = *(const bf16x8*)(lPw + L * 40 + quad * 8);
            bf16x8 pf1 = *(const bf16x8*)(lPw + (16 + L) * 40 + quad * 8);
            const int vx = ((h * 4 + quad) ^ (L & 7)) * 8;
            __builtin_amdgcn_s_setprio(1);
            #pragma unroll
            for (int dt = 0; dt < 8; ++dt) {
                bf16x8 vf = *(const bf16x8*)(lVc + (dt * 16 + L) * 128 + vx);
                acc_o[dt][0] = __builtin_amdgcn_mfma_f32_16x16x32_bf16(vf, pf0, acc_o[dt][0], 0, 0, 0);
                acc_o[dt][1] = __builtin_amdgcn_mfma_f32_16x16x32_bf16(vf, pf1, acc_o[dt][1], 0, 0, 0);
            }
            __builtin_amdgcn_s_setprio(0);
        }
    }

    const int b = bh >> 4, h = bh & 15;
    #pragma unroll
    for (int qs = 0; qs < 2; ++qs) {
        float l = lacc[qs];
        l += __shfl_xor(l, 16);
        l += __shfl_xor(l, 32);
        float inv = 1.f / l;
        size_t row = ((size_t)(b * S_LEN + q0 + wq0 + qs * 16 + L)) * (NHEAD * HSZ) + h * HSZ;
        #pragma unroll
        for (int dt = 0; dt < 8; ++dt) {
            ushort4 u;
            u.x = f2bf(acc_o[dt][qs][0] * inv);
            u.y = f2bf(acc_o[dt][qs][1] * inv);
            u.z = f2bf(acc_o[dt][qs][2] * inv);
            u.w = f2bf(acc_o[dt][qs][3] * inv);
            *(ushort4*)(O + row + dt * 16 + quad * 4) = u;
        }
    }
}

extern "C" void kernel_launch(void* const* d_in, const int* in_sizes, int n_in,
                              void* d_out, int out_size, void* d_ws, size_t ws_size,
                              hipStream_t stream) {
    const float* hidden = (const float*)d_in[0];
    const int*   pos    = (const int*)d_in[1];
    const float* Wqkv   = (const float*)d_in[2];
    const float* bqkv   = (const float*)d_in[3];
    const float* Wd     = (const float*)d_in[4];
    const float* bd     = (const float*)d_in[5];

    char* ws = (char*)d_ws;
    ushort* hA  = (ushort*)ws;                               // 16 MB (reused as O)
    ushort* WqT = (ushort*)(ws + 16777216ull);               // 24 MB
    ushort* WdT = (ushort*)(ws + 41943040ull);               //  8 MB
    ushort* Qb  = (ushort*)(ws + 50331648ull);               // 16 MB
    ushort* Kb  = (ushort*)(ws + 67108864ull);               // 16 MB
    ushort* Vb  = (ushort*)(ws + 83886080ull);               // 16 MB, V^T [bh][d][s]

    prep_kernel<<<dim3(24576), dim3(256), 0, stream>>>(hidden, hA, Wqkv, WqT, Wd, WdT);

    gemm256<0><<<dim3(24, 16), dim3(512), 0, stream>>>(hA, WqT, bqkv, nullptr, 2048, 6144,
                                                       Qb, Kb, Vb, pos);

    ushort* Obuf = hA;  // hidden bf16 no longer needed
    attn_mfma<<<dim3(8, 32), dim3(512), 0, stream>>>(Qb, Kb, Vb, Obuf);

    gemm128<<<dim3(16, 32), dim3(256), 0, stream>>>(Obuf, WdT, bd, (float*)d_out,
                                                    2048, 2048);
}